// Round 2
// baseline (381.221 us; speedup 1.0000x reference)
//
#include <hip/hip_runtime.h>

#define EPS 1e-6f
#define MAX_C 1000     // problem-fixed class count (LDS accumulator is sized by this)
#define W 32           // columns per slice: 32 floats = 128 B = full cache line
#define NCHUNKS 32     // row chunks; 8 slices * 32 chunks = 256 blocks = 1/CU (LDS-limited)
#define SBLK 1024      // 16 waves per block

// ws layout (4-byte elems):
//   [0]      int   counts[C]
//   [C]      float loss_acc
//   [C+1]    float npres_acc
//   [C+2]    int   done
//   [C+3]    float partials[NCHUNKS * C * D]   (32 MB; fully overwritten, not zeroed)
// memset zeroes the first C+3 elems only.

// Streaming scatter segment-sum. Block (slice, chunk) reads rows sequentially
// (full-BW streaming, no random gather), accumulates its 32-col slice into a
// per-class LDS array, then writes one deterministic per-chunk partial.
__global__ __launch_bounds__(SBLK)
void stream_kernel(const float* __restrict__ feats,
                   const int* __restrict__ lbls,
                   float* __restrict__ partials,
                   int* __restrict__ counts,
                   int n, int d, int nslices, int rpc, int c_total) {
    int slice = blockIdx.x % nslices;
    int chunk = blockIdx.x / nslices;
    int t    = threadIdx.x;
    int wave = t >> 6;
    int lane = t & 63;
    int rg   = lane >> 3;      // row within 8-row group
    int cg   = lane & 7;       // float4 column group within the 32-col slice

    __shared__ float smem[MAX_C * W];   // 125 KB
    int cW = c_total * W;
    for (int i = t; i < cW; i += SBLK) smem[i] = 0.0f;
    __syncthreads();

    int base = chunk * rpc;
    int rend = base + rpc;
    if (rend > n) rend = n;

    const float4* f4 = (const float4*)feats;
    int stride4 = d >> 2;                 // 64
    int colbase4 = slice * (W >> 2);      // slice * 8 (float4 units)
    int colbase  = slice * W;             // float units

    // each wave takes 16 consecutive rows per iteration as two independent
    // 8-row groups (2 float4 loads in flight per lane; 16 waves -> 32 KB/CU
    // in flight, well past the ~9 KB needed to cover HBM latency)
    for (int r0 = base + wave * 16; r0 < rend; r0 += 16 * (SBLK / 64)) {
        int rA = r0 + rg;
        int rB = rA + 8;
        bool okA = rA < rend, okB = rB < rend;
        int lA = 0, lB = 0;
        float4 vA = make_float4(0.f, 0.f, 0.f, 0.f);
        float4 vB = vA;
        if (okA) { lA = lbls[rA]; vA = f4[(size_t)rA * stride4 + colbase4 + cg]; }
        if (okB) { lB = lbls[rB]; vB = f4[(size_t)rB * stride4 + colbase4 + cg]; }

        if (slice == 0 && cg == 0) {      // count each row exactly once
            if (okA) atomicAdd(&counts[lA], 1);
            if (okB) atomicAdd(&counts[lB], 1);
        }

        // LDS scatter with per-class rotation swizzle: bank = (lc + l) & 31
        // spreads the 8 concurrent row-labels across banks (~2-way, free)
        if (okA) {
            int lc = cg << 2, b = lA * W;
            atomicAdd(&smem[b + ((lc + 0 + lA) & (W - 1))], vA.x);
            atomicAdd(&smem[b + ((lc + 1 + lA) & (W - 1))], vA.y);
            atomicAdd(&smem[b + ((lc + 2 + lA) & (W - 1))], vA.z);
            atomicAdd(&smem[b + ((lc + 3 + lA) & (W - 1))], vA.w);
        }
        if (okB) {
            int lc = cg << 2, b = lB * W;
            atomicAdd(&smem[b + ((lc + 0 + lB) & (W - 1))], vB.x);
            atomicAdd(&smem[b + ((lc + 1 + lB) & (W - 1))], vB.y);
            atomicAdd(&smem[b + ((lc + 2 + lB) & (W - 1))], vB.z);
            atomicAdd(&smem[b + ((lc + 3 + lB) & (W - 1))], vB.w);
        }
    }
    __syncthreads();

    // deterministic flush (unswizzle): partials[chunk][cls*d + colbase + lc]
    float* pbase = partials + (size_t)chunk * c_total * d;
    for (int i = t; i < cW; i += SBLK) {
        int cls  = i >> 5;             // / W
        int phys = i & (W - 1);
        int lc   = (phys - cls) & (W - 1);
        pbase[(size_t)cls * d + colbase + lc] = smem[i];
    }
}

// one block per class: sum chunk partials, Mahalanobis, global scalar reduce;
// last block to finish computes the final scalar (device-scope atomic read).
__global__ __launch_bounds__(256)
void finalize_kernel(const float* __restrict__ partials,
                     const int* __restrict__ counts,
                     const float* __restrict__ proto,
                     const float* __restrict__ cov,
                     float* __restrict__ loss_acc,
                     float* __restrict__ npres_acc,
                     int* __restrict__ done,
                     float* __restrict__ out, int c_total, int d, int nchunks) {
    int c = blockIdx.x;
    int t = threadIdx.x;
    size_t idx = (size_t)c * d + t;
    size_t cstride = (size_t)c_total * d;

    float a = 0.0f;
    for (int k = 0; k < nchunks; ++k)
        a += partials[(size_t)k * cstride + idx];

    int cnt = counts[c];
    float present = (cnt > 0) ? 1.0f : 0.0f;
    float mean = a / fmaxf((float)cnt, 1.0f);
    float diff = mean - proto[idx];
    float pe = present * diff * diff / (cov[idx] + EPS);

    for (int off = 32; off > 0; off >>= 1)
        pe += __shfl_down(pe, off, 64);
    __shared__ float s[4];
    if ((t & 63) == 0) s[t >> 6] = pe;
    __syncthreads();
    if (t == 0) {
        atomicAdd(loss_acc, (s[0] + s[1]) + (s[2] + s[3]));
        atomicAdd(npres_acc, present);
        __threadfence();
        int prev = atomicAdd(done, 1);
        if (prev == c_total - 1) {
            float L = atomicAdd(loss_acc, 0.0f);   // coherent read
            float P = atomicAdd(npres_acc, 0.0f);
            out[0] = L / (P * (float)d);
        }
    }
}

extern "C" void kernel_launch(void* const* d_in, const int* in_sizes, int n_in,
                              void* d_out, int out_size, void* d_ws, size_t ws_size,
                              hipStream_t stream) {
    const float* feats = (const float*)d_in[0];
    const int*   lbls  = (const int*)d_in[1];
    const float* proto = (const float*)d_in[2];
    const float* cov   = (const float*)d_in[3];

    int n_rows = in_sizes[1];              // N = 131072
    int d      = in_sizes[0] / n_rows;     // D = 256
    int c      = in_sizes[2] / d;          // C = 1000

    int*   counts    = (int*)d_ws;
    float* loss_acc  = (float*)d_ws + c;
    float* npres_acc = loss_acc + 1;
    int*   done      = (int*)d_ws + c + 2;
    float* partials  = (float*)d_ws + c + 3;

    hipMemsetAsync(d_ws, 0, ((size_t)c + 3) * sizeof(int), stream);

    int nslices = d / W;                               // 8
    int rpc = (n_rows + NCHUNKS - 1) / NCHUNKS;        // 4096
    stream_kernel<<<nslices * NCHUNKS, SBLK, 0, stream>>>(
        feats, lbls, partials, counts, n_rows, d, nslices, rpc, c);
    finalize_kernel<<<c, 256, 0, stream>>>(partials, counts, proto, cov,
                                           loss_acc, npres_acc, done,
                                           (float*)d_out, c, d, NCHUNKS);
}

// Round 3
// 291.609 us; speedup vs baseline: 1.3073x; 1.3073x over previous
//
#include <hip/hip_runtime.h>

#define EPS 1e-6f
#define MAX_C 1000     // problem-fixed class count
#define W 32           // columns per slice-block (acc = 1000*32*4 = 125 KB LDS)
#define NCHUNKS 32     // 8 slices * 32 chunks = 256 blocks = 1/CU
#define T 64           // rows per staged tile
#define RPC 4096       // rows per chunk (131072 / 32)
#define SBLK 1024      // 16 waves

// ws layout (4-byte elems):
//   [0]      int   counts[C]
//   [C]      float loss_acc
//   [C+1]    float npres_acc
//   [C+2]    int   done
//   [C+3]    float partials[NCHUNKS * C * D]   (32 MB; fully overwritten)
// memset zeroes the first C+3 elems only.

// LDS-privatized label histogram (replaces in-loop global count atomics).
__global__ __launch_bounds__(256)
void hist_kernel(const int* __restrict__ lbls, int* __restrict__ counts,
                 int n, int c_total) {
    __shared__ int h[MAX_C];
    for (int i = threadIdx.x; i < c_total; i += 256) h[i] = 0;
    __syncthreads();
    int tid = blockIdx.x * 256 + threadIdx.x;
    int n4 = n >> 2;
    const int4* l4 = (const int4*)lbls;
    for (int i = tid; i < n4; i += gridDim.x * 256) {
        int4 v = l4[i];
        atomicAdd(&h[v.x], 1); atomicAdd(&h[v.y], 1);
        atomicAdd(&h[v.z], 1); atomicAdd(&h[v.w], 1);
    }
    if (tid == 0)   // tail (n not multiple of 4)
        for (int i = n4 << 2; i < n; ++i) atomicAdd(&counts[lbls[i]], 1);
    __syncthreads();
    for (int i = threadIdx.x; i < c_total; i += 256)
        if (h[i] > 0) atomicAdd(&counts[i], h[i]);
}

// Streaming scatter segment-sum with ZERO in-loop atomics.
// Block (slice, chunk): streams 64-row tiles of its 32-col slice into LDS;
// wave w exclusively owns classes with (label & 15) == w, so accumulation is
// plain LDS read-add-write (no collisions by construction).
__global__ __launch_bounds__(SBLK)
void stream_kernel(const float* __restrict__ feats,
                   const int* __restrict__ lbls,
                   float* __restrict__ partials,
                   int n, int d, int nslices, int c_total) {
    int slice = blockIdx.x % nslices;
    int chunk = blockIdx.x / nslices;
    int t    = threadIdx.x;
    int w    = t >> 6;          // wave 0..15 = class-set owner
    int lane = t & 63;
    int half = lane >> 5;
    int col  = lane & 31;

    __shared__ float acc[MAX_C * W];     // 125 KB
    __shared__ float stage[T * W];       // 8 KB
    __shared__ int   lbl_s[RPC];         // 16 KB

    int cW = c_total * W;
    for (int i = t; i < cW; i += SBLK) acc[i] = 0.0f;

    int base = chunk * RPC;
    int rows = RPC; if (base + rows > n) rows = n - base;

    // stage the chunk's labels once
    for (int i = t; i < rows; i += SBLK) lbl_s[i] = lbls[base + i];

    const float* fbase = feats + (size_t)base * d + slice * W;
    int srow = t >> 3, sc = t & 7;       // 512 stager threads: 64 rows x 8 chunks
    bool stager = (t < T * 8);

    // prologue: load tile 0 into regs
    float4 ld = make_float4(0.f, 0.f, 0.f, 0.f);
    if (stager && srow < rows)
        ld = *(const float4*)(fbase + (size_t)srow * d + sc * 4);
    __syncthreads();                     // acc zeroed, labels staged
    if (stager) *(float4*)&stage[srow * W + sc * 4] = ld;
    __syncthreads();                     // tile 0 staged

    int ntiles = (rows + T - 1) / T;
    for (int tile = 0; tile < ntiles; ++tile) {
        // T14 split: issue next tile's global loads before processing this one
        int nrow0 = (tile + 1) * T;
        if (stager && nrow0 + srow < rows)
            ld = *(const float4*)(fbase + (size_t)(nrow0 + srow) * d + sc * 4);

        // process current tile: wave w handles its own classes only
        int r0 = tile * T;
        int rloc = r0 + lane;
        int lab = (rloc < rows) ? lbl_s[rloc] : -1;
        bool mine = (lab >= 0) && ((lab & 15) == w);
        unsigned long long mask = __ballot(mine);
        while (mask) {
            int rA = (int)__ffsll((unsigned long long)mask) - 1; mask &= mask - 1;
            int rB = -1;
            if (mask) { rB = (int)__ffsll((unsigned long long)mask) - 1; mask &= mask - 1; }
            int lA = __shfl(lab, rA);
            int lB = (rB >= 0) ? __shfl(lab, rB) : -1;
            int rAl = rA - r0 + r0;      // tile-local == lane index (r0 offsets cancel)
            // note: rA/rB are LANE indices == tile-local row indices
            if (rB >= 0 && lA == lB) {
                // rare same-class pair: pre-combine, half the wave writes
                if (half == 0) {
                    float v = stage[rA * W + col] + stage[rB * W + col];
                    acc[lA * W + col] += v;
                }
            } else {
                int r = half ? rB : rA;
                int l = half ? lB : lA;
                if (r >= 0)
                    acc[l * W + col] += stage[r * W + col];
            }
            (void)rAl;
        }
        __syncthreads();                 // all waves done reading stage
        if (tile + 1 < ntiles && stager)
            *(float4*)&stage[srow * W + sc * 4] = ld;  // compiler inserts vmcnt wait
        __syncthreads();                 // next tile staged
    }

    // flush: partials[chunk][cls*d + slice*W + col] — coalesced 128 B per class
    float* pbase = partials + (size_t)chunk * c_total * d + slice * W;
    for (int i = t; i < cW; i += SBLK) {
        int cls = i >> 5;                // / W
        int cc  = i & (W - 1);
        pbase[(size_t)cls * d + cc] = acc[i];
    }
}

// one block per class: sum chunk partials, Mahalanobis, global scalar reduce;
// last block to finish computes the final scalar (device-scope atomic read).
__global__ __launch_bounds__(256)
void finalize_kernel(const float* __restrict__ partials,
                     const int* __restrict__ counts,
                     const float* __restrict__ proto,
                     const float* __restrict__ cov,
                     float* __restrict__ loss_acc,
                     float* __restrict__ npres_acc,
                     int* __restrict__ done,
                     float* __restrict__ out, int c_total, int d, int nchunks) {
    int c = blockIdx.x;
    int t = threadIdx.x;
    size_t idx = (size_t)c * d + t;
    size_t cstride = (size_t)c_total * d;

    float a = 0.0f;
    for (int k = 0; k < nchunks; ++k)
        a += partials[(size_t)k * cstride + idx];

    int cnt = counts[c];
    float present = (cnt > 0) ? 1.0f : 0.0f;
    float mean = a / fmaxf((float)cnt, 1.0f);
    float diff = mean - proto[idx];
    float pe = present * diff * diff / (cov[idx] + EPS);

    for (int off = 32; off > 0; off >>= 1)
        pe += __shfl_down(pe, off, 64);
    __shared__ float s[4];
    if ((t & 63) == 0) s[t >> 6] = pe;
    __syncthreads();
    if (t == 0) {
        atomicAdd(loss_acc, (s[0] + s[1]) + (s[2] + s[3]));
        atomicAdd(npres_acc, present);
        __threadfence();
        int prev = atomicAdd(done, 1);
        if (prev == c_total - 1) {
            float L = atomicAdd(loss_acc, 0.0f);   // coherent read
            float P = atomicAdd(npres_acc, 0.0f);
            out[0] = L / (P * (float)d);
        }
    }
}

extern "C" void kernel_launch(void* const* d_in, const int* in_sizes, int n_in,
                              void* d_out, int out_size, void* d_ws, size_t ws_size,
                              hipStream_t stream) {
    const float* feats = (const float*)d_in[0];
    const int*   lbls  = (const int*)d_in[1];
    const float* proto = (const float*)d_in[2];
    const float* cov   = (const float*)d_in[3];

    int n_rows = in_sizes[1];              // N = 131072
    int d      = in_sizes[0] / n_rows;     // D = 256
    int c      = in_sizes[2] / d;          // C = 1000

    int*   counts    = (int*)d_ws;
    float* loss_acc  = (float*)d_ws + c;
    float* npres_acc = loss_acc + 1;
    int*   done      = (int*)d_ws + c + 2;
    float* partials  = (float*)d_ws + c + 3;

    hipMemsetAsync(d_ws, 0, ((size_t)c + 3) * sizeof(int), stream);

    hist_kernel<<<128, 256, 0, stream>>>(lbls, counts, n_rows, c);

    int nslices = d / W;                               // 8
    stream_kernel<<<nslices * NCHUNKS, SBLK, 0, stream>>>(
        feats, lbls, partials, n_rows, d, nslices, c);
    finalize_kernel<<<c, 256, 0, stream>>>(partials, counts, proto, cov,
                                           loss_acc, npres_acc, done,
                                           (float*)d_out, c, d, NCHUNKS);
}